// Round 2
// baseline (816.181 us; speedup 1.0000x reference)
//
#include <hip/hip_runtime.h>
#include <math.h>

#define TPB 256
#define HROWS 50
#define DDIM 128
#define NROWS 56   // 50 history + 1 news + 5 dummy (pad to 56 = 4 waves * 14 slots)

#define FMA4(A, xv, w0, w1, w2, w3)                                                              \
  A[0] = fmaf(xv.x, w0.x, A[0]); A[0] = fmaf(xv.y, w1.x, A[0]);                                  \
  A[0] = fmaf(xv.z, w2.x, A[0]); A[0] = fmaf(xv.w, w3.x, A[0]);                                  \
  A[1] = fmaf(xv.x, w0.y, A[1]); A[1] = fmaf(xv.y, w1.y, A[1]);                                  \
  A[1] = fmaf(xv.z, w2.y, A[1]); A[1] = fmaf(xv.w, w3.y, A[1]);                                  \
  A[2] = fmaf(xv.x, w0.z, A[2]); A[2] = fmaf(xv.y, w1.z, A[2]);                                  \
  A[2] = fmaf(xv.z, w2.z, A[2]); A[2] = fmaf(xv.w, w3.z, A[2]);                                  \
  A[3] = fmaf(xv.x, w0.w, A[3]); A[3] = fmaf(xv.y, w1.w, A[3]);                                  \
  A[3] = fmaf(xv.z, w2.w, A[3]); A[3] = fmaf(xv.w, w3.w, A[3]);

__global__ __launch_bounds__(TPB, 3)
void gnnrec_fused(const int* __restrict__ user_idx,
                  const int* __restrict__ news_idx,
                  const int* __restrict__ history,
                  const float* __restrict__ gnn, int NGNN,
                  const float* __restrict__ user_table,
                  const float* __restrict__ news_table,
                  const float* __restrict__ fusion_w,
                  const float* __restrict__ fusion_b,
                  const float* __restrict__ ln_g,
                  const float* __restrict__ ln_b,
                  const float* __restrict__ attn1_w,
                  const float* __restrict__ attn1_b,
                  const float* __restrict__ attn2_w,
                  const float* __restrict__ attn2_b,
                  const float* __restrict__ ut_w,
                  const float* __restrict__ ut_b,
                  const float* __restrict__ nt_w,
                  const float* __restrict__ nt_b,
                  float* __restrict__ out)
{
  __shared__ float W_s[32][128];        // 16 KB  (fusion_w k-block; reused as attn1_w [64][64])
  __shared__ float x_s[NROWS][36];      // 8.06 KB (gathered input k-block; reused as reduce scratch)
  __shared__ float hist_s[51][128];     // 26.1 KB (rows 0..49 hist_emb, row 50 = fused news emb)
  __shared__ int   idx_s[NROWS];
  __shared__ float score_s[HROWS];

  const int b    = blockIdx.x;
  const int t    = threadIdx.x;
  const int lane = t & 63;
  const int w    = t >> 6;          // wave id 0..3

  // ---------------- phase 0: indices ----------------
  if (t < HROWS)           idx_s[t] = history[b * HROWS + t];
  else if (t == HROWS)     idx_s[t] = news_idx[b];
  else if (t < NROWS)      idx_s[t] = 0;
  const int uidx = user_idx[b];
  __syncthreads();

  // ---------------- phase 1: fusion GEMM  (56 rows x 256 -> 128) ----------------
  // lane layout: ji = lane&31 -> cols j = 4*ji..4*ji+3 ; ri = lane>>5 (row split)
  // wave w owns block rows h = w + 4*ri + 8*li, li = 0..6  (bijective over 0..55)
  const int ji = lane & 31;
  const int ri = lane >> 5;
  const int hbase = w + 4 * ri;     // + 8*li

  float acc[7][4];
#pragma unroll
  for (int i = 0; i < 7; ++i)
#pragma unroll
    for (int c = 0; c < 4; ++c) acc[i][c] = 0.f;

  for (int kb = 0; kb < 8; ++kb) {
    // stage fusion_w k-block [32][128]
#pragma unroll
    for (int m = 0; m < 4; ++m) {
      int f4 = t + m * TPB;                    // 0..1023
      int kk = f4 >> 5, j4 = (f4 & 31) * 4;
      *(float4*)&W_s[kk][j4] =
          *(const float4*)&fusion_w[(size_t)(kb * 32 + kk) * 128 + j4];
    }
    // stage gathered x k-block [56][32]
#pragma unroll
    for (int pass = 0; pass < 2; ++pass) {
      int f4 = t + pass * TPB;                 // 0..447 used
      if (f4 < NROWS * 8) {
        int r = f4 >> 3, c = f4 & 7;
        int idx = idx_s[r];
        float4 v;
        if (kb < 4) {
          v = *(const float4*)&news_table[(size_t)idx * DDIM + kb * 32 + c * 4];
        } else if (idx < NGNN) {
          v = *(const float4*)&gnn[(size_t)idx * DDIM + (kb - 4) * 32 + c * 4];
        } else {
          v = make_float4(0.f, 0.f, 0.f, 0.f);
        }
        *(float4*)&x_s[r][c * 4] = v;
      }
    }
    __syncthreads();

#pragma unroll
    for (int k4 = 0; k4 < 8; ++k4) {
      float4 wv0 = *(float4*)&W_s[k4 * 4 + 0][ji * 4];
      float4 wv1 = *(float4*)&W_s[k4 * 4 + 1][ji * 4];
      float4 wv2 = *(float4*)&W_s[k4 * 4 + 2][ji * 4];
      float4 wv3 = *(float4*)&W_s[k4 * 4 + 3][ji * 4];
#pragma unroll
      for (int li = 0; li < 7; ++li) {
        float4 xv = *(float4*)&x_s[hbase + 8 * li][k4 * 4];
        FMA4(acc[li], xv, wv0, wv1, wv2, wv3);
      }
    }
    __syncthreads();
  }

  // ---- phase 1 epilogue: +bias, LayerNorm, ReLU, store hist_s ----
  {
    float4 fb = *(const float4*)&fusion_b[ji * 4];
    float4 lg = *(const float4*)&ln_g[ji * 4];
    float4 lb = *(const float4*)&ln_b[ji * 4];
#pragma unroll
    for (int li = 0; li < 7; ++li) {
      int h = hbase + 8 * li;
      float y0 = acc[li][0] + fb.x;
      float y1 = acc[li][1] + fb.y;
      float y2 = acc[li][2] + fb.z;
      float y3 = acc[li][3] + fb.w;
      float s  = y0 + y1 + y2 + y3;
      float sq = y0 * y0 + y1 * y1 + y2 * y2 + y3 * y3;
#pragma unroll
      for (int off = 1; off <= 16; off <<= 1) {   // reduce over 32 ji-lanes (stays in ri half)
        s  += __shfl_xor(s,  off);
        sq += __shfl_xor(sq, off);
      }
      float mean = s * (1.f / 128.f);
      float var  = sq * (1.f / 128.f) - mean * mean;
      float inv  = 1.f / sqrtf(var + 1e-5f);
      float r0 = fmaxf((y0 - mean) * inv * lg.x + lb.x, 0.f);
      float r1 = fmaxf((y1 - mean) * inv * lg.y + lb.y, 0.f);
      float r2 = fmaxf((y2 - mean) * inv * lg.z + lb.z, 0.f);
      float r3 = fmaxf((y3 - mean) * inv * lg.w + lb.w, 0.f);
      if (h < 51) {
        float4 o = make_float4(r0, r1, r2, r3);
        *(float4*)&hist_s[h][ji * 4] = o;
      }
    }
  }
  // (no barrier needed: next phase writes W_s only — all W_s reads completed
  //  before the kb-loop's final __syncthreads — then syncs before reading hist_s)

  // ---------------- phase 2: attention scores ----------------
  // attn1_w staged as two [64][64] chunks (fills W_s exactly) -> 4 barriers total.
  // lane layout: ci = lane&15 -> cols c = 4*ci.. ; ri2 = lane>>4
  // wave w rows: h = w + 4*ri2 + 16*li, li = 0..3  (covers 0..63; mask h>=50)
  const int ci  = lane & 15;
  const int ri2 = lane >> 4;
  float acc2[4][4];
#pragma unroll
  for (int i = 0; i < 4; ++i)
#pragma unroll
    for (int c = 0; c < 4; ++c) acc2[i][c] = 0.f;

  float* w1s = &W_s[0][0];   // reused as [64][64]
  for (int kb2 = 0; kb2 < 2; ++kb2) {
#pragma unroll
    for (int m = 0; m < 4; ++m) {
      int f4 = t + m * TPB;                    // 0..1023
      int kk = f4 >> 4, c4 = (f4 & 15) * 4;
      *(float4*)&w1s[kk * 64 + c4] =
          *(const float4*)&attn1_w[(size_t)(kb2 * 64 + kk) * 64 + c4];
    }
    __syncthreads();
#pragma unroll
    for (int k4 = 0; k4 < 16; ++k4) {
      float4 wv0 = *(float4*)&w1s[(k4 * 4 + 0) * 64 + ci * 4];
      float4 wv1 = *(float4*)&w1s[(k4 * 4 + 1) * 64 + ci * 4];
      float4 wv2 = *(float4*)&w1s[(k4 * 4 + 2) * 64 + ci * 4];
      float4 wv3 = *(float4*)&w1s[(k4 * 4 + 3) * 64 + ci * 4];
#pragma unroll
      for (int li = 0; li < 4; ++li) {
        int h  = w + 4 * ri2 + 16 * li;
        int hc = h < 51 ? h : 50;              // clamp for dummy slots
        float4 xv = *(float4*)&hist_s[hc][kb2 * 64 + k4 * 4];
        FMA4(acc2[li], xv, wv0, wv1, wv2, wv3);
      }
    }
    __syncthreads();
  }

  {
    float4 a1b = *(const float4*)&attn1_b[ci * 4];
    float4 a2w = *(const float4*)&attn2_w[ci * 4];
    float  a2b = attn2_b[0];
#pragma unroll
    for (int li = 0; li < 4; ++li) {
      int h = w + 4 * ri2 + 16 * li;
      float t0 = tanhf(acc2[li][0] + a1b.x);
      float t1 = tanhf(acc2[li][1] + a1b.y);
      float t2 = tanhf(acc2[li][2] + a1b.z);
      float t3 = tanhf(acc2[li][3] + a1b.w);
      float p = t0 * a2w.x + t1 * a2w.y + t2 * a2w.z + t3 * a2w.w;
      p += __shfl_xor(p, 1);
      p += __shfl_xor(p, 2);
      p += __shfl_xor(p, 4);
      p += __shfl_xor(p, 8);
      if (h < HROWS && ci == 0) {
        float sc = p + a2b;
        score_s[h] = (idx_s[h] != 0) ? sc : -1e9f;
      }
    }
  }
  __syncthreads();

  // ---------------- phase 3: softmax over 50 (redundant per thread; LDS broadcast) ----------------
  float mx = -3.0e38f;
  for (int r = 0; r < HROWS; ++r) mx = fmaxf(mx, score_s[r]);
  __syncthreads();
  if (t < HROWS) score_s[t] = __expf(score_s[t] - mx);
  __syncthreads();
  float denom = 0.f;
  for (int r = 0; r < HROWS; ++r) denom += score_s[r];
  const float invd = 1.f / denom;

  // ---------------- phase 4: weighted sum -> hist_repr partials ----------------
  float* red = &x_s[0][0];   // 2016 floats of scratch
  {
    int g8 = t >> 5, j4 = (t & 31) * 4;
    float p0 = 0.f, p1 = 0.f, p2 = 0.f, p3 = 0.f;
    for (int r = g8; r < HROWS; r += 8) {
      float wr = score_s[r] * invd;
      float4 hv = *(float4*)&hist_s[r][j4];
      p0 = fmaf(wr, hv.x, p0);
      p1 = fmaf(wr, hv.y, p1);
      p2 = fmaf(wr, hv.z, p2);
      p3 = fmaf(wr, hv.w, p3);
    }
    float4 o = make_float4(p0, p1, p2, p3);
    *(float4*)&red[g8 * 128 + j4] = o;
  }
  __syncthreads();

  // ---------------- phase 5: u = user_emb + hist_repr ----------------
  float* u_s  = red + 1024;
  float* ur_s = red + 1152;
  float* nr_s = red + 1280;
  if (t < 128) {
    float hr = 0.f;
#pragma unroll
    for (int g = 0; g < 8; ++g) hr += red[g * 128 + t];
    u_s[t] = user_table[(size_t)uidx * DDIM + t] + hr;
  }
  __syncthreads();

  // ---------------- phase 6: user/news transforms (128x128) ----------------
  {
    int path = t >> 7, j = t & 127;
    const float* Wm  = path ? nt_w : ut_w;
    const float* bm  = path ? nt_b : ut_b;
    const float* src = path ? &hist_s[50][0] : u_s;
    float a = 0.f;
#pragma unroll 8
    for (int k4 = 0; k4 < 32; ++k4) {
      float4 sv = *(const float4*)&src[k4 * 4];
      a = fmaf(sv.x, Wm[(size_t)(k4 * 4 + 0) * 128 + j], a);
      a = fmaf(sv.y, Wm[(size_t)(k4 * 4 + 1) * 128 + j], a);
      a = fmaf(sv.z, Wm[(size_t)(k4 * 4 + 2) * 128 + j], a);
      a = fmaf(sv.w, Wm[(size_t)(k4 * 4 + 3) * 128 + j], a);
    }
    a = fmaxf(a + bm[j], 0.f);
    (path ? nr_s : ur_s)[j] = a;
  }
  __syncthreads();

  // ---------------- phase 7: dot + sigmoid ----------------
  if (t < 64) {
    float p = ur_s[t] * nr_s[t] + ur_s[t + 64] * nr_s[t + 64];
    p += __shfl_xor(p, 1);
    p += __shfl_xor(p, 2);
    p += __shfl_xor(p, 4);
    p += __shfl_xor(p, 8);
    p += __shfl_xor(p, 16);
    p += __shfl_xor(p, 32);
    if (t == 0) out[b] = 1.f / (1.f + __expf(-p));
  }
}

extern "C" void kernel_launch(void* const* d_in, const int* in_sizes, int n_in,
                              void* d_out, int out_size, void* d_ws, size_t ws_size,
                              hipStream_t stream) {
  const int*   user_idx   = (const int*)d_in[0];
  const int*   news_idx   = (const int*)d_in[1];
  const int*   history    = (const int*)d_in[2];
  const float* gnn        = (const float*)d_in[3];
  const float* user_table = (const float*)d_in[4];
  const float* news_table = (const float*)d_in[5];
  const float* fusion_w   = (const float*)d_in[6];
  const float* fusion_b   = (const float*)d_in[7];
  const float* ln_g       = (const float*)d_in[8];
  const float* ln_b       = (const float*)d_in[9];
  const float* attn1_w    = (const float*)d_in[10];
  const float* attn1_b    = (const float*)d_in[11];
  const float* attn2_w    = (const float*)d_in[12];
  const float* attn2_b    = (const float*)d_in[13];
  const float* ut_w       = (const float*)d_in[14];
  const float* ut_b       = (const float*)d_in[15];
  const float* nt_w       = (const float*)d_in[16];
  const float* nt_b       = (const float*)d_in[17];

  const int B    = in_sizes[0];
  const int NGNN = in_sizes[3] / DDIM;
  float* out = (float*)d_out;

  gnnrec_fused<<<B, TPB, 0, stream>>>(user_idx, news_idx, history, gnn, NGNN,
                                      user_table, news_table, fusion_w, fusion_b,
                                      ln_g, ln_b, attn1_w, attn1_b, attn2_w, attn2_b,
                                      ut_w, ut_b, nt_w, nt_b, out);
}

// Round 3
// 549.836 us; speedup vs baseline: 1.4844x; 1.4844x over previous
//
#include <hip/hip_runtime.h>
#include <math.h>

typedef __attribute__((ext_vector_type(8))) short bf16x8;
typedef __attribute__((ext_vector_type(4))) float f32x4;

#define TPB 256
#define HROWS 50
#define DDIM 128

// ---------- bf16 split helpers ----------
static __device__ __forceinline__ unsigned short bf16_rne(float x) {
  union { float f; unsigned u; } v; v.f = x;
  return (unsigned short)((v.u + 0x7fffu + ((v.u >> 16) & 1u)) >> 16);
}
static __device__ __forceinline__ float bf16f(unsigned short h) {
  union { float f; unsigned u; } v; v.u = ((unsigned)h) << 16; return v.f;
}
static __device__ __forceinline__ void cvt_hilo(const float4 a, const float4 b,
                                                bf16x8& hi, bf16x8& lo) {
  unsigned short h;
  h = bf16_rne(a.x); hi[0] = (short)h; lo[0] = (short)bf16_rne(a.x - bf16f(h));
  h = bf16_rne(a.y); hi[1] = (short)h; lo[1] = (short)bf16_rne(a.y - bf16f(h));
  h = bf16_rne(a.z); hi[2] = (short)h; lo[2] = (short)bf16_rne(a.z - bf16f(h));
  h = bf16_rne(a.w); hi[3] = (short)h; lo[3] = (short)bf16_rne(a.w - bf16f(h));
  h = bf16_rne(b.x); hi[4] = (short)h; lo[4] = (short)bf16_rne(b.x - bf16f(h));
  h = bf16_rne(b.y); hi[5] = (short)h; lo[5] = (short)bf16_rne(b.y - bf16f(h));
  h = bf16_rne(b.z); hi[6] = (short)h; lo[6] = (short)bf16_rne(b.z - bf16f(h));
  h = bf16_rne(b.w); hi[7] = (short)h; lo[7] = (short)bf16_rne(b.w - bf16f(h));
}

// ws element layout (unsigned short elements):
//  fwT_hi [128][256] @ 0        fwT_lo [128][256] @ 32768
//  a1T_hi [64][128]  @ 65536    a1T_lo [64][128]  @ 73728
#define WS_FWT_LO 32768
#define WS_A1T_HI 65536
#define WS_A1T_LO 73728

// ---------- prep: transpose + split-convert weights into ws ----------
__global__ void prep_w(const float* __restrict__ fw, const float* __restrict__ a1w,
                       unsigned short* __restrict__ ws) {
  const int t = threadIdx.x, j = blockIdx.x;
  if (j < 128) {                       // fusion_w [256][128] -> fwT [128][256]
    float x = fw[(size_t)t * 128 + j];
    unsigned short hi = bf16_rne(x);
    unsigned short lo = bf16_rne(x - bf16f(hi));
    ws[j * 256 + t] = hi;
    ws[WS_FWT_LO + j * 256 + t] = lo;
  } else if (t < 128) {                // attn1_w [128][64] -> a1T [64][128]
    int jj = j - 128;                  // 0..63
    float x = a1w[(size_t)t * 64 + jj];
    unsigned short hi = bf16_rne(x);
    unsigned short lo = bf16_rne(x - bf16f(hi));
    ws[WS_A1T_HI + jj * 128 + t] = hi;
    ws[WS_A1T_LO + jj * 128 + t] = lo;
  }
}

// ---------- main fused kernel ----------
__global__ __launch_bounds__(TPB, 3)
void gnnrec_mfma(const int* __restrict__ user_idx,
                 const int* __restrict__ news_idx,
                 const int* __restrict__ history,
                 const float* __restrict__ gnn, int NGNN,
                 const float* __restrict__ user_table,
                 const float* __restrict__ news_table,
                 const float* __restrict__ fusion_b,
                 const float* __restrict__ ln_g,
                 const float* __restrict__ ln_b,
                 const float* __restrict__ attn1_b,
                 const float* __restrict__ attn2_w,
                 const float* __restrict__ attn2_b,
                 const float* __restrict__ ut_w,
                 const float* __restrict__ ut_b,
                 const float* __restrict__ nt_w,
                 const float* __restrict__ nt_b,
                 const unsigned short* __restrict__ ws,
                 float* __restrict__ out)
{
  // W chunk, k-contiguous fragment layout: [col][k], row stride 40 shorts
  // (80 B: 16B-aligned frags; 20-word stride -> even 8-lanes-per-bank-quad = no net conflict)
  __shared__ short WtH[128][40];       // 10.0 KB
  __shared__ short WtL[128][40];       // 10.0 KB
  __shared__ float hist_s[51][132];    // 26.3 KB (pad 132 breaks row-major bank aliasing)
  __shared__ float scratch[1024 + 384];// 5.5 KB  (phase 4/5 reductions)
  __shared__ int   idx_s[64];
  __shared__ float score_s[HROWS];

  const int b    = blockIdx.x;
  const int t    = threadIdx.x;
  const int lane = t & 63;
  const int w    = t >> 6;             // wave 0..3
  const int c15  = lane & 15;          // fragment row/col index
  const int g    = lane >> 4;          // k-group 0..3

  // ---------------- phase 0: indices ----------------
  if (t < HROWS)        idx_s[t] = history[b * HROWS + t];
  else if (t == HROWS)  idx_s[t] = news_idx[b];
  else if (t < 64)      idx_s[t] = 0;
  const int uidx = user_idx[b];
  __syncthreads();

  // ---------------- phase 1: fusion GEMM via MFMA (64x256 @ 256x128) ----------------
  // wave w owns output rows 16w..16w+15 (rows 0..50 real, rest pad), all 128 cols.
  const int arow = 16 * w + c15;                    // A row this lane supplies
  const int aidx = idx_s[arow];
  const float* news_row = news_table + (size_t)aidx * DDIM;
  const bool   gnn_ok   = aidx < NGNN;
  const float* gnn_row  = gnn + (size_t)(gnn_ok ? aidx : 0) * DDIM;

  f32x4 acc[8];
#pragma unroll
  for (int ct = 0; ct < 8; ++ct) acc[ct] = (f32x4){0.f, 0.f, 0.f, 0.f};

  const int sc = t >> 1, ss = (t & 1) * 16;         // staging: col, elem-offset

  for (int kb = 0; kb < 8; ++kb) {
    // stage W chunk (cols 0..127 x k 32) from pre-transposed ws, hi+lo
    {
      const unsigned short* ph = ws + sc * 256 + kb * 32 + ss;
      const unsigned short* pl = ph + WS_FWT_LO;
      bf16x8 h0 = *(const bf16x8*)(ph);
      bf16x8 h1 = *(const bf16x8*)(ph + 8);
      bf16x8 l0 = *(const bf16x8*)(pl);
      bf16x8 l1 = *(const bf16x8*)(pl + 8);
      *(bf16x8*)&WtH[sc][ss]     = h0;
      *(bf16x8*)&WtH[sc][ss + 8] = h1;
      *(bf16x8*)&WtL[sc][ss]     = l0;
      *(bf16x8*)&WtL[sc][ss + 8] = l1;
    }
    // A fragment: direct gather of 8 floats (k = 32kb + 8g + 0..7), cvt to hi/lo
    float4 x0 = make_float4(0.f, 0.f, 0.f, 0.f);
    float4 x1 = make_float4(0.f, 0.f, 0.f, 0.f);
    if (kb < 4) {
      const float* p = news_row + kb * 32 + g * 8;
      x0 = *(const float4*)(p);
      x1 = *(const float4*)(p + 4);
    } else if (gnn_ok) {
      const float* p = gnn_row + (kb - 4) * 32 + g * 8;
      x0 = *(const float4*)(p);
      x1 = *(const float4*)(p + 4);
    }
    bf16x8 aH, aL;
    cvt_hilo(x0, x1, aH, aL);
    __syncthreads();

#pragma unroll
    for (int ct = 0; ct < 8; ++ct) {
      bf16x8 bH = *(const bf16x8*)&WtH[16 * ct + c15][g * 8];
      bf16x8 bL = *(const bf16x8*)&WtL[16 * ct + c15][g * 8];
      acc[ct] = __builtin_amdgcn_mfma_f32_16x16x32_bf16(aH, bH, acc[ct], 0, 0, 0);
      acc[ct] = __builtin_amdgcn_mfma_f32_16x16x32_bf16(aH, bL, acc[ct], 0, 0, 0);
      acc[ct] = __builtin_amdgcn_mfma_f32_16x16x32_bf16(aL, bH, acc[ct], 0, 0, 0);
    }
    __syncthreads();
  }

  // ---- phase 1 epilogue: +bias, LayerNorm (in-wave), ReLU -> hist_s ----
  {
    float fbv[8], lgv[8], lbv[8];
#pragma unroll
    for (int ct = 0; ct < 8; ++ct) {
      fbv[ct] = fusion_b[16 * ct + c15];
      lgv[ct] = ln_g[16 * ct + c15];
      lbv[ct] = ln_b[16 * ct + c15];
    }
#pragma unroll
    for (int reg = 0; reg < 4; ++reg) {
      // C layout: row = 16w + 4g + reg, col = 16ct + c15
      float y[8];
      float s = 0.f, sq = 0.f;
#pragma unroll
      for (int ct = 0; ct < 8; ++ct) {
        y[ct] = acc[ct][reg] + fbv[ct];
        s += y[ct];
        sq += y[ct] * y[ct];
      }
#pragma unroll
      for (int off = 1; off <= 8; off <<= 1) {  // reduce over 16-lane col group
        s  += __shfl_xor(s,  off);
        sq += __shfl_xor(sq, off);
      }
      float mean = s * (1.f / 128.f);
      float var  = sq * (1.f / 128.f) - mean * mean;
      float inv  = 1.f / sqrtf(var + 1e-5f);
      int row = 16 * w + 4 * g + reg;
      if (row < 51) {
#pragma unroll
        for (int ct = 0; ct < 8; ++ct) {
          float r = fmaxf((y[ct] - mean) * inv * lgv[ct] + lbv[ct], 0.f);
          hist_s[row][16 * ct + c15] = r;
        }
      }
    }
  }
  __syncthreads();

  // ---------------- phase 2: attention scores via MFMA (64x128 @ 128x64) ----------------
  const unsigned short* a1T_hi = ws + WS_A1T_HI;
  const unsigned short* a1T_lo = ws + WS_A1T_LO;
  const int hrow = (16 * w + c15) < 51 ? (16 * w + c15) : 50;

  f32x4 acc2[4];
#pragma unroll
  for (int ct = 0; ct < 4; ++ct) acc2[ct] = (f32x4){0.f, 0.f, 0.f, 0.f};

#pragma unroll
  for (int ks = 0; ks < 4; ++ks) {
    float4 h0 = *(const float4*)&hist_s[hrow][ks * 32 + g * 8];
    float4 h1 = *(const float4*)&hist_s[hrow][ks * 32 + g * 8 + 4];
    bf16x8 aH, aL;
    cvt_hilo(h0, h1, aH, aL);
#pragma unroll
    for (int ct = 0; ct < 4; ++ct) {
      const int col = 16 * ct + c15;
      bf16x8 bH = *(const bf16x8*)(a1T_hi + col * 128 + ks * 32 + g * 8);
      bf16x8 bL = *(const bf16x8*)(a1T_lo + col * 128 + ks * 32 + g * 8);
      acc2[ct] = __builtin_amdgcn_mfma_f32_16x16x32_bf16(aH, bH, acc2[ct], 0, 0, 0);
      acc2[ct] = __builtin_amdgcn_mfma_f32_16x16x32_bf16(aH, bL, acc2[ct], 0, 0, 0);
      acc2[ct] = __builtin_amdgcn_mfma_f32_16x16x32_bf16(aL, bH, acc2[ct], 0, 0, 0);
    }
  }

  // ---- phase 2 epilogue: tanh, attn2 dot, in-wave reduce -> score_s ----
  {
    float a1bv[4], a2wv[4];
#pragma unroll
    for (int ct = 0; ct < 4; ++ct) {
      a1bv[ct] = attn1_b[16 * ct + c15];
      a2wv[ct] = attn2_w[16 * ct + c15];
    }
    const float a2b = attn2_b[0];
#pragma unroll
    for (int reg = 0; reg < 4; ++reg) {
      float p = 0.f;
#pragma unroll
      for (int ct = 0; ct < 4; ++ct)
        p += tanhf(acc2[ct][reg] + a1bv[ct]) * a2wv[ct];
#pragma unroll
      for (int off = 1; off <= 8; off <<= 1) p += __shfl_xor(p, off);
      int row = 16 * w + 4 * g + reg;
      if (row < HROWS && c15 == 0)
        score_s[row] = (idx_s[row] != 0) ? (p + a2b) : -1e9f;
    }
  }
  __syncthreads();

  // ---------------- phase 3: softmax over 50 (redundant per thread) ----------------
  float mx = -3.0e38f;
  for (int r = 0; r < HROWS; ++r) mx = fmaxf(mx, score_s[r]);
  __syncthreads();
  if (t < HROWS) score_s[t] = __expf(score_s[t] - mx);
  __syncthreads();
  float denom = 0.f;
  for (int r = 0; r < HROWS; ++r) denom += score_s[r];
  const float invd = 1.f / denom;

  // ---------------- phase 4: weighted sum -> hist_repr partials ----------------
  float* red = scratch;
  {
    int g8 = t >> 5, j4 = (t & 31) * 4;
    float p0 = 0.f, p1 = 0.f, p2 = 0.f, p3 = 0.f;
    for (int r = g8; r < HROWS; r += 8) {
      float wr = score_s[r] * invd;
      float4 hv = *(const float4*)&hist_s[r][j4];
      p0 = fmaf(wr, hv.x, p0);
      p1 = fmaf(wr, hv.y, p1);
      p2 = fmaf(wr, hv.z, p2);
      p3 = fmaf(wr, hv.w, p3);
    }
    *(float4*)&red[g8 * 128 + j4] = make_float4(p0, p1, p2, p3);
  }
  __syncthreads();

  // ---------------- phase 5: u = user_emb + hist_repr ----------------
  float* u_s  = scratch + 1024;
  float* ur_s = scratch + 1152;
  float* nr_s = scratch + 1280;
  if (t < 128) {
    float hr = 0.f;
#pragma unroll
    for (int q = 0; q < 8; ++q) hr += red[q * 128 + t];
    u_s[t] = user_table[(size_t)uidx * DDIM + t] + hr;
  }
  __syncthreads();

  // ---------------- phase 6: user/news transforms (128x128, fp32 VALU) ----------------
  {
    int path = t >> 7, j = t & 127;
    const float* Wm  = path ? nt_w : ut_w;
    const float* bm  = path ? nt_b : ut_b;
    const float* src = path ? &hist_s[50][0] : u_s;
    float a = 0.f;
#pragma unroll 8
    for (int k4 = 0; k4 < 32; ++k4) {
      float4 sv = *(const float4*)&src[k4 * 4];
      a = fmaf(sv.x, Wm[(size_t)(k4 * 4 + 0) * 128 + j], a);
      a = fmaf(sv.y, Wm[(size_t)(k4 * 4 + 1) * 128 + j], a);
      a = fmaf(sv.z, Wm[(size_t)(k4 * 4 + 2) * 128 + j], a);
      a = fmaf(sv.w, Wm[(size_t)(k4 * 4 + 3) * 128 + j], a);
    }
    a = fmaxf(a + bm[j], 0.f);
    (path ? nr_s : ur_s)[j] = a;
  }
  __syncthreads();

  // ---------------- phase 7: dot + sigmoid ----------------
  if (t < 64) {
    float p = ur_s[t] * nr_s[t] + ur_s[t + 64] * nr_s[t + 64];
    p += __shfl_xor(p, 1);
    p += __shfl_xor(p, 2);
    p += __shfl_xor(p, 4);
    p += __shfl_xor(p, 8);
    p += __shfl_xor(p, 16);
    p += __shfl_xor(p, 32);
    if (t == 0) out[b] = 1.f / (1.f + __expf(-p));
  }
}

extern "C" void kernel_launch(void* const* d_in, const int* in_sizes, int n_in,
                              void* d_out, int out_size, void* d_ws, size_t ws_size,
                              hipStream_t stream) {
  const int*   user_idx   = (const int*)d_in[0];
  const int*   news_idx   = (const int*)d_in[1];
  const int*   history    = (const int*)d_in[2];
  const float* gnn        = (const float*)d_in[3];
  const float* user_table = (const float*)d_in[4];
  const float* news_table = (const float*)d_in[5];
  const float* fusion_w   = (const float*)d_in[6];
  const float* fusion_b   = (const float*)d_in[7];
  const float* ln_g       = (const float*)d_in[8];
  const float* ln_b       = (const float*)d_in[9];
  const float* attn1_w    = (const float*)d_in[10];
  const float* attn1_b    = (const float*)d_in[11];
  const float* attn2_w    = (const float*)d_in[12];
  const float* attn2_b    = (const float*)d_in[13];
  const float* ut_w       = (const float*)d_in[14];
  const float* ut_b       = (const float*)d_in[15];
  const float* nt_w       = (const float*)d_in[16];
  const float* nt_b       = (const float*)d_in[17];

  const int B    = in_sizes[0];
  const int NGNN = in_sizes[3] / DDIM;
  float* out = (float*)d_out;
  unsigned short* ws = (unsigned short*)d_ws;

  // prep: transpose + split-convert weights into ws (160 KB)
  prep_w<<<192, 256, 0, stream>>>(fusion_w, attn1_w, ws);

  gnnrec_mfma<<<B, TPB, 0, stream>>>(user_idx, news_idx, history, gnn, NGNN,
                                     user_table, news_table, fusion_b,
                                     ln_g, ln_b, attn1_b, attn2_w, attn2_b,
                                     ut_w, ut_b, nt_w, nt_b, ws, out);
}